// Round 1
// baseline (161.605 us; speedup 1.0000x reference)
//
#include <hip/hip_runtime.h>

typedef __attribute__((ext_vector_type(8))) short short8;
typedef __attribute__((ext_vector_type(4))) float f32x4;
typedef __attribute__((ext_vector_type(4))) unsigned short us4;

__device__ __forceinline__ unsigned short f2bf(float f){
  unsigned int u = __float_as_uint(f);
  u = (u + 0x7FFFu + ((u >> 16) & 1u)) >> 16;
  return (unsigned short)u;
}
__device__ __forceinline__ float bf2f(unsigned short h){
  return __uint_as_float(((unsigned int)h) << 16);
}

// ---------------- weight f32 -> bf16 cast ----------------
__global__ __launch_bounds__(256)
void cvt_w(const float* __restrict__ wq, const float* __restrict__ wo,
           unsigned short* __restrict__ wqb, unsigned short* __restrict__ wob){
  int i = blockIdx.x * 256 + threadIdx.x;           // float4 index
  const int n1 = 1536 * 1024 / 4;
  float4 v = (i < n1) ? ((const float4*)wq)[i] : ((const float4*)wo)[i - n1];
  us4 o = { f2bf(v.x), f2bf(v.y), f2bf(v.z), f2bf(v.w) };
  if (i < n1) ((us4*)wqb)[i] = o;
  else        ((us4*)wob)[i - n1] = o;
}

// ---------------- RMSNorm over D=1024, f32 -> bf16 ----------------
__global__ __launch_bounds__(256)
void rmsnorm_x(const float* __restrict__ x, unsigned short* __restrict__ h){
  int row = blockIdx.x, t = threadIdx.x;
  float4 v = ((const float4*)(x + (size_t)row * 1024))[t];
  float ss = v.x*v.x + v.y*v.y + v.z*v.z + v.w*v.w;
  #pragma unroll
  for (int m = 1; m < 64; m <<= 1) ss += __shfl_xor(ss, m);
  __shared__ float wsum[4];
  if ((t & 63) == 0) wsum[t >> 6] = ss;
  __syncthreads();
  float tot = wsum[0] + wsum[1] + wsum[2] + wsum[3];
  float sc = rsqrtf(tot * (1.f/1024.f) + 1.1920929e-07f);
  us4 o = { f2bf(v.x*sc), f2bf(v.y*sc), f2bf(v.z*sc), f2bf(v.w*sc) };
  *(us4*)(h + (size_t)row * 1024 + t * 4) = o;
}

// ---------------- NT GEMM: C[M,N] = A[M,K] * B[N,K]^T (bf16 in, f32 acc) ----
// 128x128 tile, BK=64, 4 waves (2x2), each wave 64x64 via 4x4 mfma_16x16x32.
template<bool BF_OUT, bool RES>
__global__ __launch_bounds__(256)
void gemm_nt(const unsigned short* __restrict__ A, const unsigned short* __restrict__ B,
             int M, int N, int K, float* __restrict__ Cf, unsigned short* __restrict__ Cb,
             const float* __restrict__ resid){
  constexpr int RS = 72;                    // LDS row stride in shorts (144B, 2-way-free banks)
  __shared__ short As[128 * RS];
  __shared__ short Bs[128 * RS];
  const int nbn = N >> 7;
  const int bm = blockIdx.x / nbn;
  const int bn = blockIdx.x % nbn;
  const int t = threadIdx.x;
  const int lane = t & 63;
  const int wv = t >> 6;
  const int wm = (wv >> 1) * 64, wn = (wv & 1) * 64;
  const int lr = lane & 15, lg = lane >> 4;

  f32x4 acc[4][4];
  #pragma unroll
  for (int m = 0; m < 4; m++)
    #pragma unroll
    for (int n = 0; n < 4; n++) acc[m][n] = (f32x4){0.f,0.f,0.f,0.f};

  const unsigned short* Ab = A + (size_t)(bm * 128) * K;
  const unsigned short* Bb = B + (size_t)(bn * 128) * K;

  for (int kt = 0; kt < K; kt += 64) {
    #pragma unroll
    for (int i = 0; i < 4; i++) {
      int slot = t + i * 256;
      int row = slot >> 3, cg = slot & 7;
      short8 va = *(const short8*)(Ab + (size_t)row * K + kt + cg * 8);
      short8 vb = *(const short8*)(Bb + (size_t)row * K + kt + cg * 8);
      *(short8*)&As[row * RS + cg * 8] = va;
      *(short8*)&Bs[row * RS + cg * 8] = vb;
    }
    __syncthreads();
    #pragma unroll
    for (int kk = 0; kk < 2; kk++) {
      short8 af[4], bfr[4];
      #pragma unroll
      for (int m = 0; m < 4; m++) af[m] = *(const short8*)&As[(wm + m*16 + lr)*RS + kk*32 + lg*8];
      #pragma unroll
      for (int n = 0; n < 4; n++) bfr[n] = *(const short8*)&Bs[(wn + n*16 + lr)*RS + kk*32 + lg*8];
      #pragma unroll
      for (int m = 0; m < 4; m++)
        #pragma unroll
        for (int n = 0; n < 4; n++)
          acc[m][n] = __builtin_amdgcn_mfma_f32_16x16x32_bf16(af[m], bfr[n], acc[m][n], 0, 0, 0);
    }
    __syncthreads();
  }
  #pragma unroll
  for (int m = 0; m < 4; m++)
    #pragma unroll
    for (int n = 0; n < 4; n++)
      #pragma unroll
      for (int r = 0; r < 4; r++) {
        int grow = bm*128 + wm + m*16 + lg*4 + r;
        int gcol = bn*128 + wn + n*16 + lr;
        size_t idx = (size_t)grow * N + gcol;
        if (BF_OUT) { Cb[idx] = f2bf(acc[m][n][r]); }
        else {
          float v = acc[m][n][r];
          if (RES) v += resid[idx];
          Cf[idx] = v;
        }
      }
}

// ---------------- per-head RMSNorm + RoPE, split/layout q,k,v ----------------
// one wave per (row, head); lane = dim. heads 0-15: q, 16-19: k, 20-23: v.
__global__ __launch_bounds__(256)
void post_qkv(const unsigned short* __restrict__ qkv,
              unsigned short* __restrict__ Qb, unsigned short* __restrict__ Kb,
              unsigned short* __restrict__ Vt){
  int w = blockIdx.x * 4 + (threadIdx.x >> 6);
  int lane = threadIdx.x & 63;
  int head = w % 24;
  int row  = w / 24;                       // [0, 4096)
  int b = row >> 11, pos = row & 2047;
  int off = head < 16 ? head * 64 : (head < 20 ? 1024 + (head-16)*64 : 1280 + (head-20)*64);
  float val = bf2f(qkv[(size_t)row * 1536 + off + lane]);
  if (head < 20) {
    float ss = val * val;
    #pragma unroll
    for (int m = 1; m < 64; m <<= 1) ss += __shfl_xor(ss, m);
    val *= rsqrtf(ss * (1.f/64.f) + 1.1920929e-07f);
    float part = __shfl_xor(val, 32);
    int i = lane & 31;
    float f = (float)pos * exp2f((float)i * (-13.287712379549449f / 32.f));
    float s, c; sincosf(f, &s, &c);
    val = (lane < 32) ? (val * c - part * s) : (part * s + val * c);
  }
  unsigned short o = f2bf(val);
  if (head < 16)      Qb[((size_t)((b*16 + head     )*2048 + pos))*64 + lane] = o;
  else if (head < 20) Kb[((size_t)((b*4  + head - 16)*2048 + pos))*64 + lane] = o;
  else                Vt[((size_t)((b*4  + head - 20)*64 + lane))*2048 + pos] = o; // transposed
}

// ---------------- lo[q] = max(q-1023, last reset <= q); auto-detect mask dtype --
__global__ __launch_bounds__(256)
void compute_lo(const unsigned char* __restrict__ mb, int* __restrict__ lo){
  int b = blockIdx.x, t = threadIdx.x;
  __shared__ int flag_s;
  if (t == 0) flag_s = 0;
  __syncthreads();
  if (t < 64 && (t & 3) != 0 && mb[t] != 0) atomicOr(&flag_s, 1); // byte-mask detector
  __syncthreads();
  const bool isb = (flag_s != 0);
  const int* mi = (const int*)mb;
  int tmax = 0;
  int mvals[8];
  #pragma unroll
  for (int j = 0; j < 8; j++) {
    int p = t * 8 + j;
    int mv = isb ? (int)mb[b*2048 + p] : mi[b*2048 + p];
    mvals[j] = mv;
    if (mv) tmax = p;
  }
  __shared__ int sm[256];
  sm[t] = tmax;
  __syncthreads();
  for (int offd = 1; offd < 256; offd <<= 1) {
    int v = (t >= offd) ? sm[t - offd] : 0;
    __syncthreads();
    if (t >= offd) sm[t] = max(sm[t], v);
    __syncthreads();
  }
  int run = (t > 0) ? sm[t - 1] : 0;
  #pragma unroll
  for (int j = 0; j < 8; j++) {
    int p = t * 8 + j;
    if (mvals[j]) run = p;
    int l = run, wlo = p - 1023;
    if (wlo > l) l = wlo;
    if (l < 0) l = 0;
    lo[b*2048 + p] = l;
  }
}

// ---------------- attention: one wave = 16 queries, contiguous key range ------
__global__ __launch_bounds__(256)
void attn(const unsigned short* __restrict__ Qb, const unsigned short* __restrict__ Kb,
          const unsigned short* __restrict__ Vt, const int* __restrict__ lo,
          unsigned short* __restrict__ Y){
  int blk = blockIdx.x;
  int qt = blk & 31, h = (blk >> 5) & 15, b = blk >> 9;
  int wv = threadIdx.x >> 6, lane = threadIdx.x & 63;
  int lr = lane & 15, lg = lane >> 4;
  int q0 = qt * 64 + wv * 16;
  const unsigned short* Qh = Qb + ((size_t)(b*16 + h)) * 2048 * 64;
  int kvh = h >> 2;
  const unsigned short* Kh = Kb + ((size_t)(b*4 + kvh)) * 2048 * 64;
  const unsigned short* Vh = Vt + ((size_t)(b*4 + kvh)) * 64 * 2048;
  short8 qa0 = *(const short8*)(Qh + (size_t)(q0 + lr) * 64 + lg * 8);
  short8 qa1 = *(const short8*)(Qh + (size_t)(q0 + lr) * 64 + 32 + lg * 8);
  const int* lop = lo + b * 2048 + q0;
  int4 mlv = *(const int4*)(lop + lg * 4);
  int mylo[4] = {mlv.x, mlv.y, mlv.z, mlv.w};
  int kc0 = lop[0] & ~31;
  int kend = q0 + 15;
  f32x4 oacc[4];
  #pragma unroll
  for (int n = 0; n < 4; n++) oacc[n] = (f32x4){0.f,0.f,0.f,0.f};
  float den[4] = {0.f,0.f,0.f,0.f};
  __shared__ __align__(16) short Pl[4][16 * 40];
  short* Pw = Pl[wv];
  for (int kc = kc0; kc <= kend; kc += 32) {
    f32x4 s[2];
    #pragma unroll
    for (int n = 0; n < 2; n++) {
      int kr = kc + n*16 + lr;
      int krl = min(kr, 2047);
      short8 k0 = *(const short8*)(Kh + (size_t)krl * 64 + lg * 8);
      short8 k1 = *(const short8*)(Kh + (size_t)krl * 64 + 32 + lg * 8);
      f32x4 z = (f32x4){0.f,0.f,0.f,0.f};
      z = __builtin_amdgcn_mfma_f32_16x16x32_bf16(qa0, k0, z, 0, 0, 0);
      z = __builtin_amdgcn_mfma_f32_16x16x32_bf16(qa1, k1, z, 0, 0, 0);
      s[n] = z;
    }
    #pragma unroll
    for (int n = 0; n < 2; n++)
      #pragma unroll
      for (int r = 0; r < 4; r++) {
        int krow = kc + n*16 + lr;
        int qrow = q0 + lg*4 + r;
        bool valid = (krow >= mylo[r]) && (krow <= qrow);
        float p = valid ? __expf(s[n][r] * 0.125f) : 0.f;
        den[r] += p;
        Pw[(lg*4 + r) * 40 + n*16 + lr] = (short)f2bf(p);
      }
    short8 pa = *(const short8*)&Pw[lr * 40 + lg * 8];
    int vc = min(kc + lg * 8, 2040);
    #pragma unroll
    for (int n = 0; n < 4; n++) {
      short8 vb = *(const short8*)(Vh + (size_t)(n*16 + lr) * 2048 + vc);
      oacc[n] = __builtin_amdgcn_mfma_f32_16x16x32_bf16(pa, vb, oacc[n], 0, 0, 0);
    }
  }
  #pragma unroll
  for (int r = 0; r < 4; r++)
    #pragma unroll
    for (int m = 1; m < 16; m <<= 1) den[r] += __shfl_xor(den[r], m);
  #pragma unroll
  for (int n = 0; n < 4; n++)
    #pragma unroll
    for (int r = 0; r < 4; r++) {
      int qrow = q0 + lg*4 + r;
      Y[((size_t)(b*2048 + qrow)) * 1024 + h*64 + n*16 + lr] = f2bf(oacc[n][r] / den[r]);
    }
}

extern "C" void kernel_launch(void* const* d_in, const int* in_sizes, int n_in,
                              void* d_out, int out_size, void* d_ws, size_t ws_size,
                              hipStream_t stream){
  const float* x    = (const float*)d_in[0];
  const float* wqkv = (const float*)d_in[1];
  const float* wout = (const float*)d_in[2];
  const unsigned char* mask = (const unsigned char*)d_in[3];
  float* out = (float*)d_out;
  char* ws = (char*)d_ws;
  size_t off = 0;
  auto alloc = [&](size_t bytes) -> void* {
    void* p = ws + off;
    off += (bytes + 255) & ~(size_t)255;
    return p;
  };
  unsigned short* wq_b  = (unsigned short*)alloc((size_t)1536*1024*2);
  unsigned short* wo_b  = (unsigned short*)alloc((size_t)1024*1024*2);
  unsigned short* h_b   = (unsigned short*)alloc((size_t)4096*1024*2);
  unsigned short* qkv_b = (unsigned short*)alloc((size_t)4096*1536*2);
  unsigned short* q_b   = (unsigned short*)alloc((size_t)4096*1024*2);
  unsigned short* k_b   = (unsigned short*)alloc((size_t)4096*256*2);
  unsigned short* vt_b  = (unsigned short*)alloc((size_t)4096*256*2);
  unsigned short* y_b   = (unsigned short*)alloc((size_t)4096*1024*2);
  int* lo               = (int*)alloc((size_t)4096*4);

  cvt_w<<<2560, 256, 0, stream>>>(wqkv, wout, wq_b, wo_b);
  rmsnorm_x<<<4096, 256, 0, stream>>>(x, h_b);
  gemm_nt<true,  false><<<32*12, 256, 0, stream>>>(h_b, wq_b, 4096, 1536, 1024, nullptr, qkv_b, nullptr);
  post_qkv<<<24576, 256, 0, stream>>>(qkv_b, q_b, k_b, vt_b);
  compute_lo<<<2, 256, 0, stream>>>(mask, lo);
  attn<<<1024, 256, 0, stream>>>(q_b, k_b, vt_b, lo, y_b);
  gemm_nt<false, true><<<32*8, 256, 0, stream>>>(y_b, wo_b, 4096, 1024, 1024, out, nullptr, x);
}